// Round 1
// baseline (240.388 us; speedup 1.0000x reference)
//
#include <hip/hip_runtime.h>

// QRDQN n-step TD error. B=16384, N=32, TAU=64, NSTEP=5, gamma=0.99.
// out[0] = loss, out[1..B] = td_err_per_sample.
// Compute-bound on fp32 VALU: 67M quantile pairs x ~7 ops.

#define B_TOTAL 16384
#define N_ACT 32
#define TAU 64
#define NSTEP 5
#define GAMMA 0.99f
#define WPB 4  // waves per block

__global__ __launch_bounds__(256) void qrdqn_td_kernel(
    const float* __restrict__ q,
    const float* __restrict__ next_n_q,
    const int*   __restrict__ action,
    const int*   __restrict__ next_n_action,
    const float* __restrict__ reward,
    const float* __restrict__ done,
    const float* __restrict__ weight,
    float* __restrict__ out_td,      // d_out + 1 (B entries)
    float* __restrict__ ws_partial)  // per-block partial sums of td*weight
{
    const int lane = threadIdx.x & 63;
    const int wave = threadIdx.x >> 6;
    int b = blockIdx.x * WPB + wave;
    b = __builtin_amdgcn_readfirstlane(b);   // wave-uniform: scalarize loads

    const int   act  = action[b];
    const int   nact = next_n_action[b];
    const float dn   = done[b];
    const float wgt  = weight[b];

    // n-step discounted reward: r = sum_i gamma^i * reward[i, b]
    float r = 0.0f, g = 1.0f;
    #pragma unroll
    for (int i = 0; i < NSTEP; ++i) {
        r += g * reward[i * B_TOTAL + b];
        g *= GAMMA;
    }
    // g == gamma^NSTEP  (the module's default value_gamma path)
    const float vg = g * (1.0f - dn);

    // coalesced row gathers: 64 lanes read 64 consecutive floats
    const float qsa = q[((size_t)b * N_ACT + act) * TAU + lane];
    const float tq  = next_n_q[((size_t)b * N_ACT + nact) * TAU + lane];
    const float target = r + vg * tq;   // lane holds target quantile j

    // accumulate sum over (i, j) pairs; lane j, loop i broadcast via readlane
    float acc = 0.0f;
    #pragma unroll
    for (int i = 0; i < TAU; ++i) {
        const float qi = __shfl(qsa, i, 64);        // q_s_a[i], literal lane -> v_readlane
        const float u  = target - qi;
        const float a  = fabsf(u);
        const float m  = fminf(a, 1.0f);            // huber(k=1): m*(a - 0.5m)
        const float f  = m * (a - 0.5f * m);        // == 0.5u^2 (|u|<=1) else |u|-0.5
        const float tau_i = ((float)i + 0.5f) * (1.0f / (float)TAU);
        const float w  = (u <= 0.0f) ? (1.0f - tau_i) : tau_i;  // |tau_hat - 1{u<=0}|
        acc = fmaf(f, w, acc);
    }

    // wave butterfly reduce: sum over lanes (= sum over j)
    #pragma unroll
    for (int off = 32; off > 0; off >>= 1)
        acc += __shfl_xor(acc, off, 64);
    const float td = acc * (1.0f / (float)TAU);   // mean over i (sum_j kept)

    __shared__ float sred[WPB];
    if (lane == 0) {
        out_td[b]  = td;
        sred[wave] = td * wgt;
    }
    __syncthreads();
    if (threadIdx.x == 0) {
        float s = 0.0f;
        #pragma unroll
        for (int i = 0; i < WPB; ++i) s += sred[i];
        ws_partial[blockIdx.x] = s;
    }
}

__global__ __launch_bounds__(256) void qrdqn_loss_kernel(
    const float* __restrict__ part, float* __restrict__ out_loss, int n)
{
    float s = 0.0f;
    for (int i = threadIdx.x; i < n; i += 256) s += part[i];
    #pragma unroll
    for (int off = 32; off > 0; off >>= 1)
        s += __shfl_xor(s, off, 64);
    __shared__ float sr[4];
    const int wave = threadIdx.x >> 6;
    if ((threadIdx.x & 63) == 0) sr[wave] = s;
    __syncthreads();
    if (threadIdx.x == 0) {
        out_loss[0] = (sr[0] + sr[1] + sr[2] + sr[3]) * (1.0f / (float)B_TOTAL);
    }
}

extern "C" void kernel_launch(void* const* d_in, const int* in_sizes, int n_in,
                              void* d_out, int out_size, void* d_ws, size_t ws_size,
                              hipStream_t stream)
{
    const float* q       = (const float*)d_in[0];
    const float* nq      = (const float*)d_in[1];
    const int*   act     = (const int*)d_in[2];
    const int*   nact    = (const int*)d_in[3];
    const float* reward  = (const float*)d_in[4];
    const float* done    = (const float*)d_in[5];
    const float* weight  = (const float*)d_in[6];
    float* out = (float*)d_out;

    float* ws_partial = (float*)d_ws;            // 4096 floats
    const int nblocks = B_TOTAL / WPB;           // 4096

    qrdqn_td_kernel<<<nblocks, 256, 0, stream>>>(
        q, nq, act, nact, reward, done, weight, out + 1, ws_partial);
    qrdqn_loss_kernel<<<1, 256, 0, stream>>>(ws_partial, out, nblocks);
}